// Round 4
// baseline (86.296 us; speedup 1.0000x reference)
//
#include <hip/hip_runtime.h>

#define BB 8
#define NC 12
#define NC1 11
#define HH 512
#define WW 512
#define NG 64      // 8-h groups per column
#define GH 8       // h per group

static constexpr size_t CH = (size_t)HH * WW;   // 262144

// output offsets (flat floats, in return order)
static constexpr size_t OFF_LSM   = 0;
static constexpr size_t OFF_CLP   = (size_t)BB * NC1 * CH;                 // 23068672
static constexpr size_t OFF_CLEAN = OFF_CLP + (size_t)BB * NC1 * WW;       // 23113728
static constexpr size_t OFF_STD   = OFF_CLEAN + (size_t)BB * NC * CH;      // 48279552
static constexpr size_t OFF_TOPO  = OFF_STD + (size_t)BB * NC1 * WW;
static constexpr size_t OFF_CONT  = OFF_TOPO + (size_t)BB * (NC1 - 1) * WW;
static constexpr size_t OFF_CURV  = OFF_CONT + (size_t)BB * NC1 * (WW - 1);

// workspace (floats)
static constexpr size_t WS_BASE = 0;                                     // [88][64][512] normalized cum bases
static constexpr size_t WS_LOG  = WS_BASE + (size_t)BB * NC1 * NG * WW;  // [88][512]
static constexpr size_t WS_LP   = WS_LOG + (size_t)BB * NC1 * WW;        // [88][512]
// total ~11.9 MB

// ---------------------------------------------------------------- KA: streaming stats
// grid (8 wtiles, 11 c, 8 b) = 704 blocks; 512 thr = 64 w x 8 h-slabs; 20KB LDS
__global__ __launch_bounds__(512) void ka_stats(const float* __restrict__ in,
                                                float* __restrict__ ws,
                                                float* __restrict__ out) {
    const int w = threadIdx.x & 63;      // 0..63
    const int s = threadIdx.x >> 6;      // slab 0..7 (64 h each)
    const int wt = blockIdx.x;           // 0..7
    const int c  = blockIdx.y, b = blockIdx.z;
    const int bc = b * NC1 + c;
    const int w0 = wt * 64;

    __shared__ float gE[NG][64];         // [group][w] 16KB -> later bases
    __shared__ float gP[8][64];
    __shared__ float gQ[8][64];

    const float* p = in + (size_t)(b * NC + c) * CH + (size_t)(s * 64) * WW + w0 + w;
    float P = 0.f, Q = 0.f;
#pragma unroll
    for (int j = 0; j < 8; ++j) {
        float E = 0.f;
#pragma unroll
        for (int i = 0; i < GH; ++i) {
            const int h = s * 64 + j * GH + i;
            const float e = expf(p[(size_t)(j * GH + i) * WW]);
            const float hf = (float)h;
            E += e; P += hf * e; Q += hf * hf * e;
        }
        gE[s * 8 + j][w] = E;
    }
    gP[s][w] = P; gQ[s][w] = Q;
    __syncthreads();

    if (threadIdx.x < 64) {
        float S = 0.f;
#pragma unroll
        for (int g = 0; g < NG; ++g) S += gE[g][w];
        const float inv = 1.f / S;
        float run = 0.f;
#pragma unroll
        for (int g = 0; g < NG; ++g) {     // prefix: normalized cum BEFORE group g
            const float e = gE[g][w];
            gE[g][w] = run * inv;
            run += e;
        }
        float Pt = 0.f, Qt = 0.f;
#pragma unroll
        for (int s2 = 0; s2 < 8; ++s2) { Pt += gP[s2][w]; Qt += gQ[s2][w]; }
        const float lp = Pt * inv;
        float var = Qt * inv - lp * lp; if (var < 0.f) var = 0.f;
        const size_t o = (size_t)bc * WW + w0 + w;
        ws[WS_LOG + o] = logf(S);
        ws[WS_LP + o]  = lp;
        out[OFF_STD + o] = sqrtf(var);
    }
    __syncthreads();

    // all 8 waves cooperatively store bases (coalesced 256B/instr)
#pragma unroll
    for (int j = 0; j < 8; ++j)
        ws[WS_BASE + ((size_t)bc * NG + s * 8 + j) * WW + w0 + w] = gE[s * 8 + j][w];
}

// ---------------------------------------------------------------- KB: lsm + clean_masks (+ smalls on g==0)
// grid (64 h-groups, 8 b) = 512 blocks; 256 thr x float2 = 512 w
__global__ __launch_bounds__(256) void kb_emit(const float* __restrict__ in,
                                               const float* __restrict__ ws,
                                               float* __restrict__ out) {
    const int t = threadIdx.x;
    const int g = blockIdx.x;   // 0..63
    const int b = blockIdx.y;   // 0..7
    const int w = t * 2;

    float2 cum[NC1], lgs[NC1];
#pragma unroll
    for (int c = 0; c < NC1; ++c) {
        const size_t bc = (size_t)(b * NC1 + c);
        cum[c] = *(const float2*)(ws + WS_BASE + (bc * NG + g) * WW + w);
        lgs[c] = *(const float2*)(ws + WS_LOG + bc * WW + w);
    }
    const float* ip  = in + (size_t)b * NC * CH + (size_t)(g * GH) * WW + w;
    float* lsm = out + OFF_LSM + (size_t)b * NC1 * CH + (size_t)(g * GH) * WW + w;
    float* cln = out + OFF_CLEAN + (size_t)b * NC * CH + (size_t)(g * GH) * WW + w;

    for (int i = 0; i < GH; ++i) {
        const size_t ho = (size_t)i * WW;
        float2 x[NC1];
#pragma unroll
        for (int c = 0; c < NC1; ++c)
            x[c] = *(const float2*)(ip + (size_t)c * CH + ho);
#pragma unroll
        for (int c = 0; c < NC1; ++c) {
            const float lx = x[c].x - lgs[c].x;
            const float ly = x[c].y - lgs[c].y;
            *(float2*)(lsm + (size_t)c * CH + ho) = make_float2(lx, ly);
            cum[c].x += expf(lx);           // sm = exp(log_softmax)
            cum[c].y += expf(ly);
        }
        float2 tc = cum[0];
        *(float2*)(cln + ho) = make_float2(1.f - tc.x, 1.f - tc.y);
#pragma unroll
        for (int k = 1; k < NC1; ++k) {
            const float2 t2 = make_float2(fmaxf(cum[k].x + tc.x - 1.f, 0.f),
                                          fmaxf(cum[k].y + tc.y - 1.f, 0.f));
            *(float2*)(cln + (size_t)k * CH + ho) = make_float2(tc.x - t2.x, tc.y - t2.y);
            tc = t2;
        }
        *(float2*)(cln + (size_t)NC1 * CH + ho) = tc;
    }

    if (g != 0) return;
    // ---- smalls: cummax / topology / continuity / curvature from lp
    const float CM[NC1] = {1.2261f, 1.1558f, 1.1161f, 1.1195f, 2.7202f, 2.3714f,
                           1.7055f, 3.2717f, 2.6716f, 5.0418f, 0.4293f};
    const float* lp = ws + WS_LP;
#pragma unroll
    for (int sdx = 0; sdx < 2; ++sdx) {
        const int wv = w + sdx;
        const int wm = (wv - 5 < 0) ? 0 : wv - 5;
        const int wp = (wv + 5 > WW - 1) ? WW - 1 : wv + 5;
        float m = 0.f, prev = 0.f;
        for (int c = 0; c < NC1; ++c) {
            const size_t rb = (size_t)(b * NC1 + c) * WW;
            const float lv = lp[rb + wv];
            m = (c == 0) ? lv : fmaxf(m, lv);
            out[OFF_CLP + rb + wv] = m;
            if (c > 0)
                out[OFF_TOPO + (size_t)(b * (NC1 - 1) + (c - 1)) * WW + wv] =
                    fmaxf(prev - lv, 0.f);
            prev = lv;
            if (wv < WW - 1) {
                const float nxt = lp[rb + wv + 1];
                out[OFF_CONT + (size_t)(b * NC1 + c) * (WW - 1) + wv] = fabsf(lv - nxt);
            }
            const float a  = lp[rb + wm];
            const float bb = lp[rb + wp];
            const float fo = bb - a;
            const float so = a - 2.f * lv + bb;
            const float bs = 1.f + fo * fo;
            out[OFF_CURV + rb + wv] = fabsf(so / (bs * sqrtf(bs))) - CM[c];
        }
    }
}

extern "C" void kernel_launch(void* const* d_in, const int* in_sizes, int n_in,
                              void* d_out, int out_size, void* d_ws, size_t ws_size,
                              hipStream_t stream) {
    const float* in = (const float*)d_in[0];
    float* out = (float*)d_out;
    float* ws = (float*)d_ws;

    hipLaunchKernelGGL(ka_stats, dim3(8, NC1, BB), dim3(512), 0, stream, in, ws, out);
    hipLaunchKernelGGL(kb_emit, dim3(NG, BB), dim3(256), 0, stream, in, ws, out);
}

// Round 5
// 78.400 us; speedup vs baseline: 1.1007x; 1.1007x over previous
//
#include <hip/hip_runtime.h>

#define BB 8
#define NC 12
#define NC1 11
#define HH 512
#define WW 512
#define NCH 32     // 16-h chunks per column
#define HC 16
#define NBC (BB*NC1) // 88

static constexpr size_t CH = (size_t)HH * WW;   // 262144

// output offsets (flat floats, in return order)
static constexpr size_t OFF_LSM   = 0;
static constexpr size_t OFF_CLP   = (size_t)BB * NC1 * CH;                 // 23068672
static constexpr size_t OFF_CLEAN = OFF_CLP + (size_t)BB * NC1 * WW;       // 23113728
static constexpr size_t OFF_STD   = OFF_CLEAN + (size_t)BB * NC * CH;      // 48279552
static constexpr size_t OFF_TOPO  = OFF_STD + (size_t)BB * NC1 * WW;
static constexpr size_t OFF_CONT  = OFF_TOPO + (size_t)BB * (NC1 - 1) * WW;
static constexpr size_t OFF_CURV  = OFF_CONT + (size_t)BB * NC1 * (WW - 1);

// workspace layout (floats)
static constexpr size_t WS_E    = 0;                              // [88][32][512] -> later chunk cum-bases
static constexpr size_t WS_P    = (size_t)NBC * NCH * WW;         // 1441792
static constexpr size_t WS_Q    = 2 * WS_P;
static constexpr size_t WS_INV  = 3 * WS_P;                       // [88][512]
static constexpr size_t WS_LOG  = WS_INV + (size_t)NBC * WW;
static constexpr size_t WS_LP   = WS_LOG + (size_t)NBC * WW;

// ---------------------------------------------------------------- K1: chunk partials (float4 streaming)
// grid (8 chunk-groups, 88 bc) = 704 blocks x 512 thr; no barriers
__global__ __launch_bounds__(512) void k1_partials(const float* __restrict__ in,
                                                   float* __restrict__ ws) {
    const int w4 = threadIdx.x & 127;     // float4 lane: w = 4*w4
    const int cg = threadIdx.x >> 7;      // 0..3
    const int chunk = blockIdx.x * 4 + cg;
    const int bc = blockIdx.y;
    const int b = bc / NC1, c = bc % NC1;

    const float* p = in + ((size_t)(b * NC + c) * HH + (size_t)chunk * HC) * WW + 4 * w4;
    float4 E = make_float4(0.f, 0.f, 0.f, 0.f);
    float4 P = E, Q = E;
#pragma unroll
    for (int i = 0; i < HC; ++i) {
        const float4 x = *(const float4*)(p + (size_t)i * WW);
        const float h = (float)(chunk * HC + i);
        const float ex = expf(x.x), ey = expf(x.y), ez = expf(x.z), ew = expf(x.w);
        E.x += ex; E.y += ey; E.z += ez; E.w += ew;
        P.x += h * ex; P.y += h * ey; P.z += h * ez; P.w += h * ew;
        Q.x += h * h * ex; Q.y += h * h * ey; Q.z += h * h * ez; Q.w += h * h * ew;
    }
    const size_t o = ((size_t)bc * NCH + chunk) * WW + 4 * w4;
    *(float4*)(ws + WS_E + o) = E;
    *(float4*)(ws + WS_P + o) = P;
    *(float4*)(ws + WS_Q + o) = Q;
}

// ---------------------------------------------------------------- K2: per-column reduce, bases, std
__global__ __launch_bounds__(512) void k2_reduce(float* __restrict__ ws,
                                                 float* __restrict__ out) {
    const int w = threadIdx.x;
    const int bc = blockIdx.x;  // 0..87

    const size_t base0 = (size_t)bc * NCH * WW + w;
    float Ee[NCH];
    float S = 0.f, P = 0.f, Q = 0.f;
#pragma unroll
    for (int k = 0; k < NCH; ++k) {
        const float e = ws[WS_E + base0 + (size_t)k * WW];
        Ee[k] = e;
        S += e;
        P += ws[WS_P + base0 + (size_t)k * WW];
        Q += ws[WS_Q + base0 + (size_t)k * WW];
    }
    const float inv = 1.f / S;
    float pre = 0.f;
#pragma unroll
    for (int k = 0; k < NCH; ++k) {  // normalized cumsum base BEFORE each chunk (in place over E)
        ws[WS_E + base0 + (size_t)k * WW] = pre * inv;
        pre += Ee[k];
    }
    const float lp = P * inv;
    float var = Q * inv - lp * lp;
    if (var < 0.f) var = 0.f;

    const size_t o = (size_t)bc * WW + w;
    ws[WS_INV + o] = inv;
    ws[WS_LOG + o] = logf(S);
    ws[WS_LP + o]  = lp;
    out[OFF_STD + o] = sqrtf(var);
}

// ---------------------------------------------------------------- K4: lsm + clean_masks (nt stores) + smalls
// grid (2 whalf, 32 chunk, 8 b) = 512 blocks x 256 thr
__global__ __launch_bounds__(256) void k4_main(const float* __restrict__ in,
                                               const float* __restrict__ ws,
                                               float* __restrict__ out) {
    const int t = threadIdx.x;
    const int wh = blockIdx.x, chunk = blockIdx.y, b = blockIdx.z;
    const int w = wh * 256 + t;

    float cum[NC1], inv[NC1], lgs[NC1];
#pragma unroll
    for (int c = 0; c < NC1; ++c) {
        const size_t bc = (size_t)(b * NC1 + c);
        cum[c] = ws[WS_E + (bc * NCH + chunk) * WW + w];
        inv[c] = ws[WS_INV + bc * WW + w];
        lgs[c] = ws[WS_LOG + bc * WW + w];
    }

    const float* ip = in + (size_t)b * NC * CH + (size_t)(chunk * HC) * WW + w;
    float* lsm = out + OFF_LSM + (size_t)b * NC1 * CH + (size_t)(chunk * HC) * WW + w;
    float* cln = out + OFF_CLEAN + (size_t)b * NC * CH + (size_t)(chunk * HC) * WW + w;

    for (int i = 0; i < HC; ++i) {
        const size_t ho = (size_t)i * WW;
        float x[NC1];
#pragma unroll
        for (int c = 0; c < NC1; ++c)
            x[c] = ip[(size_t)c * CH + ho];
#pragma unroll
        for (int c = 0; c < NC1; ++c) {
            cum[c] += expf(x[c]) * inv[c];
            __builtin_nontemporal_store(x[c] - lgs[c], lsm + (size_t)c * CH + ho);
        }
        float tc = cum[0];
        __builtin_nontemporal_store(1.f - tc, cln + ho);
#pragma unroll
        for (int k = 1; k < NC1; ++k) {
            const float t2 = fmaxf(cum[k] + tc - 1.f, 0.f);
            __builtin_nontemporal_store(tc - t2, cln + (size_t)k * CH + ho);
            tc = t2;
        }
        __builtin_nontemporal_store(tc, cln + (size_t)NC1 * CH + ho);
    }

    if (chunk != 0) return;
    // ---- smalls: cummax / topology / continuity / curvature from lp
    const float CM[NC1] = {1.2261f, 1.1558f, 1.1161f, 1.1195f, 2.7202f, 2.3714f,
                           1.7055f, 3.2717f, 2.6716f, 5.0418f, 0.4293f};
    const float* lp = ws + WS_LP;
    const int wm = (w - 5 < 0) ? 0 : w - 5;
    const int wp = (w + 5 > WW - 1) ? WW - 1 : w + 5;
    float m = 0.f, prev = 0.f;
    for (int c = 0; c < NC1; ++c) {
        const size_t rb = (size_t)(b * NC1 + c) * WW;
        const float lv = lp[rb + w];
        m = (c == 0) ? lv : fmaxf(m, lv);
        out[OFF_CLP + rb + w] = m;
        if (c > 0)
            out[OFF_TOPO + (size_t)(b * (NC1 - 1) + (c - 1)) * WW + w] = fmaxf(prev - lv, 0.f);
        prev = lv;
        if (w < WW - 1) {
            const float nxt = lp[rb + w + 1];
            out[OFF_CONT + (size_t)(b * NC1 + c) * (WW - 1) + w] = fabsf(lv - nxt);
        }
        const float a  = lp[rb + wm];
        const float bb = lp[rb + wp];
        const float fo = bb - a;
        const float so = a - 2.f * lv + bb;
        const float bs = 1.f + fo * fo;
        out[OFF_CURV + rb + w] = fabsf(so / (bs * sqrtf(bs))) - CM[c];
    }
}

extern "C" void kernel_launch(void* const* d_in, const int* in_sizes, int n_in,
                              void* d_out, int out_size, void* d_ws, size_t ws_size,
                              hipStream_t stream) {
    const float* in = (const float*)d_in[0];
    float* out = (float*)d_out;
    float* ws = (float*)d_ws;

    hipLaunchKernelGGL(k1_partials, dim3(NCH / 4, NBC), dim3(512), 0, stream, in, ws);
    hipLaunchKernelGGL(k2_reduce, dim3(NBC), dim3(512), 0, stream, ws, out);
    hipLaunchKernelGGL(k4_main, dim3(2, NCH, BB), dim3(256), 0, stream, in, ws, out);
}